// Round 2
// baseline (1295.465 us; speedup 1.0000x reference)
//
#include <hip/hip_runtime.h>
#include <math.h>

#define DEV __device__ __forceinline__

typedef __attribute__((ext_vector_type(8))) short frag8;     // 8 x bf16 (4 VGPRs)
typedef __attribute__((ext_vector_type(4))) float facc4;     // MFMA accumulator
typedef __attribute__((ext_vector_type(4))) unsigned short us4;

DEV float bf2f(unsigned short u){ union{unsigned i; float f;} x; x.i=((unsigned)u)<<16; return x.f; }
DEV unsigned short f2bf(float f){ union{float f; unsigned i;} x; x.f=f;
  return (unsigned short)((x.i + 0x7FFFu + ((x.i>>16)&1u))>>16); }

// direct global->LDS DMA, 16B per lane. LDS dest is wave-uniform base + lane*16.
#define GLD16(g, l) __builtin_amdgcn_global_load_lds( \
    (const __attribute__((address_space(1))) void*)(g), \
    (__attribute__((address_space(3))) void*)(l), 16, 0, 0)

// Stage a ROWSx64 bf16 tile (K-major rows, ld elements) into LDS with XOR-8
// chunk swizzle: LDS chunk (r,cg) holds global chunk (r, cg^(r&7)).
template<int ROWS>
DEV void stage_tile(const unsigned short* __restrict__ g0, int ld, unsigned short* s0){
  static_assert(ROWS % 8 == 0, "");
  constexpr int SLOTS = ROWS/8;
  const int w = threadIdx.x>>6, lane = threadIdx.x&63;
  for (int s = w; s < SLOTS; s += 4) {
    int c  = (s<<6) + lane;
    int r  = c >> 3, cg = c & 7;
    int kg = cg ^ (r & 7);
    GLD16(g0 + (size_t)r*ld + (kg<<3), s0 + (s<<9));
  }
}

DEV frag8 frag_ld(const unsigned short* s, int row, int kg){
  int cg = kg ^ (row & 7);
  return *(const frag8*)(s + (row<<6) + (cg<<3));
}

// C[BM][BN] += A[BM][K] * Bt[BN][K]^T, K consumed in kIters chunks of 64.
template<int BM, int BN, int WR, int WC>
DEV void gemm_core(const unsigned short* __restrict__ Ag, int lda,
                   const unsigned short* __restrict__ Bg, int ldb,
                   int kIters, unsigned short* As, unsigned short* Bs,
                   facc4 (&acc)[BM/(WR*16)][BN/(WC*16)]) {
  constexpr int WM = BM/(WR*16), WN = BN/(WC*16);
  const int tid = threadIdx.x, w = tid>>6, lane = tid&63;
  const int wr = w / WC, wc = w % WC;
  const int col = lane & 15, quad = lane >> 4;
  for (int kt = 0; kt < kIters; ++kt) {
    stage_tile<BM>(Ag + kt*64, lda, As);
    stage_tile<BN>(Bg + kt*64, ldb, Bs);
    __syncthreads();
    #pragma unroll
    for (int ks = 0; ks < 2; ++ks) {
      frag8 af[WM], bfr[WN];
      #pragma unroll
      for (int i=0;i<WM;++i) af[i]  = frag_ld(As, wr*WM*16 + i*16 + col, ks*4+quad);
      #pragma unroll
      for (int j=0;j<WN;++j) bfr[j] = frag_ld(Bs, wc*WN*16 + j*16 + col, ks*4+quad);
      #pragma unroll
      for (int i=0;i<WM;++i)
        #pragma unroll
        for (int j=0;j<WN;++j)
          acc[i][j] = __builtin_amdgcn_mfma_f32_16x16x32_bf16(af[i], bfr[j], acc[i][j], 0,0,0);
    }
    __syncthreads();
  }
}

#define ZERO_ACC(acc, I, J) { facc4 zz = {0.f,0.f,0.f,0.f}; \
  _Pragma("unroll") for(int i_=0;i_<I;++i_) _Pragma("unroll") for(int j_=0;j_<J;++j_) acc[i_][j_]=zz; }

// ---------------- prep kernels ----------------
__global__ void k_transpose(const float* __restrict__ in, unsigned short* __restrict__ out,
                            int K, int N){  // in[K][N] -> out[N][K] bf16
  __shared__ float tile[32][33];
  int bx = blockIdx.x*32, by = blockIdx.y*32;
  int tx = threadIdx.x&31, ty = threadIdx.x>>5;
  for(int j=ty;j<32;j+=8) tile[j][tx] = in[(size_t)(by+j)*N + bx+tx];
  __syncthreads();
  for(int j=ty;j<32;j+=8) out[(size_t)(bx+j)*K + by+tx] = f2bf(tile[tx][j]);
}

__global__ void k_cvt(const float* __restrict__ in, unsigned short* __restrict__ out, int n){
  int i = blockIdx.x*256 + threadIdx.x;
  if(i<n) out[i]=f2bf(in[i]);
}

__global__ void k_vones(unsigned short* __restrict__ Vt){  // Vt row 64 = 1.0 per head
  int i = blockIdx.x*256+threadIdx.x;       // 64*4096
  int head=i>>12, n=i&4095;
  Vt[((size_t)head*80+64)*4096 + n] = 0x3F80;
}

// ---------------- QKV projection ----------------
__global__ __launch_bounds__(256,2) void k_qkv(const unsigned short* __restrict__ xb,
    const unsigned short* __restrict__ wqkvT,
    const float* __restrict__ bq, const float* __restrict__ bk, const float* __restrict__ bv,
    unsigned short* __restrict__ Qb, unsigned short* __restrict__ Kb, unsigned short* __restrict__ Vt){
  __shared__ __align__(16) unsigned short As[128*64];
  __shared__ __align__(16) unsigned short Bs[128*64];
  facc4 acc[4][4]; ZERO_ACC(acc,4,4)
  const int bm = blockIdx.x, bn = blockIdx.y;
  gemm_core<128,128,2,2>(xb + (size_t)bm*128*1024, 1024,
                         wqkvT + (size_t)bn*128*1024, 1024, 16, As, Bs, acc);
  const int tid=threadIdx.x, w=tid>>6, lane=tid&63, col=lane&15, quad=lane>>4;
  const int wr=w>>1, wc=w&1;
  #pragma unroll
  for(int i=0;i<4;++i){
    int row0 = bm*128 + wr*64 + i*16 + quad*4;
    int bb = row0 >> 12, n0 = row0 & 4095;
    #pragma unroll
    for(int j=0;j<4;++j){
      int c = bn*128 + wc*64 + j*16 + col;
      int region = c >> 10, f = c & 1023, he = f >> 6, hd = f & 63;
      const float* bias = (region==0)? bq : (region==1)? bk : bv;
      float bsv = bias[f];
      if(region < 2){
        unsigned short* dst = (region==0? Qb : Kb) + ((size_t)(bb*16+he)*4096 + n0)*64 + hd;
        #pragma unroll
        for(int r=0;r<4;++r) dst[(size_t)r*64] = f2bf(acc[i][j][r] + bsv);
      } else {
        us4 pk;
        #pragma unroll
        for(int r=0;r<4;++r) pk[r] = f2bf(acc[i][j][r] + bsv);
        *(us4*)(Vt + ((size_t)(bb*16+he)*80 + hd)*4096 + n0) = pk;
      }
    }
  }
}

// ---------------- FAVOR+ features (per head-quarter of 16 heads) ----------------
__global__ __launch_bounds__(256,2) void k_featq(const unsigned short* __restrict__ Qb,
    const unsigned short* __restrict__ projB, unsigned short* __restrict__ Qp, int qbase){
  __shared__ __align__(16) unsigned short As[64*64];
  __shared__ __align__(16) unsigned short Bs[256*64];
  __shared__ float diagS[64];
  facc4 acc[1][16]; ZERO_ACC(acc,1,16)
  const int br = blockIdx.x;                       // 1024 blocks = 16 heads * 64
  gemm_core<64,256,4,1>(Qb + ((size_t)(qbase*1024 + br))*4096, 64, projB, 64, 1, As, Bs, acc);
  if (threadIdx.x < 64){
    int t=threadIdx.x; float ss=0.f;
    #pragma unroll
    for(int kg=0;kg<8;++kg){ int cg=kg^(t&7); const unsigned short* p = As + t*64 + cg*8;
      #pragma unroll
      for(int e=0;e<8;++e){ float v=bf2f(p[e]); ss+=v*v; } }
    diagS[t]=0.0625f*ss;                            // 0.5 * dn^2
  }
  __syncthreads();
  const int w=threadIdx.x>>6, lane=threadIdx.x&63, col=lane&15, quad=lane>>4;
  const float dn=0.35355339059327378f;
  float mx[4];
  #pragma unroll
  for(int r=0;r<4;++r){ float m=-1e30f;
    #pragma unroll
    for(int j=0;j<16;++j) m=fmaxf(m, acc[0][j][r]);
    #pragma unroll
    for(int d=1; d<16; d<<=1) m=fmaxf(m, __shfl_xor(m,d));
    mx[r]=m*dn;
  }
  size_t tok0 = (size_t)br*64;
  #pragma unroll
  for(int j=0;j<16;++j){
    #pragma unroll
    for(int r=0;r<4;++r){
      int t = w*16 + quad*4 + r;
      float dd = dn*acc[0][j][r];
      Qp[(tok0 + t)*256 + j*16 + col] = f2bf(0.0625f*(expf(dd - diagS[t] - mx[r]) + 1e-4f));
    }
  }
}

__global__ __launch_bounds__(256,2) void k_featk_max(const unsigned short* __restrict__ Kb,
    const unsigned short* __restrict__ projB, float* __restrict__ pmax){
  __shared__ __align__(16) unsigned short As[64*64];
  __shared__ __align__(16) unsigned short Bs[256*64];
  __shared__ float wm[4];
  facc4 acc[1][16]; ZERO_ACC(acc,1,16)
  const int br = blockIdx.x;                       // 4096 (all heads)
  gemm_core<64,256,4,1>(Kb + (size_t)br*64*64, 64, projB, 64, 1, As, Bs, acc);
  const int w=threadIdx.x>>6, lane=threadIdx.x&63;
  float m=-1e30f;
  #pragma unroll
  for(int j=0;j<16;++j)
    #pragma unroll
    for(int r=0;r<4;++r) m=fmaxf(m, acc[0][j][r]);
  #pragma unroll
  for(int d=1; d<64; d<<=1) m=fmaxf(m, __shfl_xor(m,d));
  if(lane==0) wm[w]=m;
  __syncthreads();
  if(threadIdx.x==0)
    pmax[br] = fmaxf(fmaxf(wm[0],wm[1]),fmaxf(wm[2],wm[3])) * 0.35355339059327378f;
}

__global__ void k_mxk(const float* __restrict__ pmax, float* __restrict__ mxK){
  int h = threadIdx.x;  // 64
  float m=-1e30f;
  for(int i=0;i<64;++i) m=fmaxf(m, pmax[h*64+i]);
  mxK[h]=m;
}

__global__ __launch_bounds__(256,2) void k_featk(const unsigned short* __restrict__ Kb,
    const unsigned short* __restrict__ projB, const float* __restrict__ mxK,
    unsigned short* __restrict__ KpT, int qbase){
  __shared__ __align__(16) unsigned short As[64*64];
  __shared__ __align__(16) unsigned short Bs[256*64];
  __shared__ float diagS[64];
  facc4 acc[1][16]; ZERO_ACC(acc,1,16)
  const int br = blockIdx.x;                       // 1024
  gemm_core<64,256,4,1>(Kb + ((size_t)(qbase*1024 + br))*4096, 64, projB, 64, 1, As, Bs, acc);
  if (threadIdx.x < 64){
    int t=threadIdx.x; float ss=0.f;
    #pragma unroll
    for(int kg=0;kg<8;++kg){ int cg=kg^(t&7); const unsigned short* p = As + t*64 + cg*8;
      #pragma unroll
      for(int e=0;e<8;++e){ float v=bf2f(p[e]); ss+=v*v; } }
    diagS[t]=0.0625f*ss;
  }
  __syncthreads();
  const int lh = br >> 6;
  const float mxh = mxK[qbase*16 + lh];
  const int w=threadIdx.x>>6, lane=threadIdx.x&63, col=lane&15, quad=lane>>4;
  const int n0 = (br&63)*64 + w*16 + quad*4;
  const float dn=0.35355339059327378f;
  #pragma unroll
  for(int j=0;j<16;++j){
    us4 pk;
    #pragma unroll
    for(int r=0;r<4;++r){
      int t = w*16 + quad*4 + r;
      float dd = dn*acc[0][j][r];
      pk[r] = f2bf(0.0625f*(expf(dd - diagS[t] - mxh) + 1e-4f));
    }
    *(us4*)(KpT + ((size_t)lh*256 + j*16 + col)*4096 + n0) = pk;  // [M][N] transposed
  }
}

// ---------------- kv = Kp^T V (split-K 16 over tokens), +ones row ----------------
__global__ __launch_bounds__(256,2) void k_kv(const unsigned short* __restrict__ KpT,
    const unsigned short* __restrict__ Vt, float* __restrict__ part, int qbase){
  __shared__ __align__(16) unsigned short As[256*64];
  __shared__ __align__(16) unsigned short Bs[80*64];
  facc4 acc[4][5]; ZERO_ACC(acc,4,5)
  const int ksp = blockIdx.x, lh = blockIdx.y;     // 16 x 16
  gemm_core<256,80,4,1>(KpT + (size_t)lh*1048576 + ksp*256, 4096,
                        Vt  + ((size_t)(qbase*16+lh))*327680 + ksp*256, 4096, 4, As, Bs, acc);
  const int w=threadIdx.x>>6, lane=threadIdx.x&63, col=lane&15, quad=lane>>4;
  #pragma unroll
  for(int i=0;i<4;++i){
    int mp0 = w*64 + i*16 + quad*4;
    #pragma unroll
    for(int j=0;j<5;++j){
      int d = j*16+col;
      *(facc4*)(part + (((size_t)(ksp*16 + lh))*80 + d)*256 + mp0) = acc[i][j];
    }
  }
}

__global__ void k_kvred(const float* __restrict__ part, unsigned short* __restrict__ kvT, int qbase){
  int i = blockIdx.x*256 + threadIdx.x;            // 16*80*256 = 327680
  float s=0.f;
  #pragma unroll
  for(int ks=0;ks<16;++ks) s += part[(size_t)ks*327680 + i];
  kvT[(size_t)qbase*327680 + i] = f2bf(s);
}

// ---------------- attn = Qp kv / (Qp s) ----------------
__global__ __launch_bounds__(256,2) void k_attn(const unsigned short* __restrict__ Qp,
    const unsigned short* __restrict__ kvT, unsigned short* __restrict__ attnOut, int qbase){
  __shared__ __align__(16) unsigned short As[128*64];
  __shared__ __align__(16) unsigned short Bs[80*64];
  facc4 acc[2][5]; ZERO_ACC(acc,2,5)
  const int mb = blockIdx.x, lh = blockIdx.y;      // 32 x 16
  gemm_core<128,80,4,1>(Qp  + (size_t)lh*1048576 + (size_t)mb*32768, 256,
                        kvT + ((size_t)(qbase*16+lh))*20480, 256, 4, As, Bs, acc);
  const int w=threadIdx.x>>6, lane=threadIdx.x&63, col=lane&15, quad=lane>>4;
  const int gh = qbase*16 + lh, b = gh>>4, h = gh&15;
  #pragma unroll
  for(int i=0;i<2;++i){
    #pragma unroll
    for(int r=0;r<4;++r){
      float den = __shfl(acc[i][4][r], lane & 48); // col 64 for this quad's rows
      float inv = 1.0f/den;
      int n = mb*128 + w*32 + i*16 + quad*4 + r;
      size_t base = ((size_t)(b*4096 + n))*1024 + h*64;
      #pragma unroll
      for(int j=0;j<4;++j)
        attnOut[base + j*16 + col] = f2bf(acc[i][j][r]*inv);
    }
  }
}

// ---------------- output projection + residual ----------------
__global__ __launch_bounds__(256,2) void k_oproj(const unsigned short* __restrict__ attnOut,
    const unsigned short* __restrict__ woT, const float* __restrict__ bo,
    const float* __restrict__ x, float* __restrict__ y1){
  __shared__ __align__(16) unsigned short As[128*64];
  __shared__ __align__(16) unsigned short Bs[128*64];
  facc4 acc[4][4]; ZERO_ACC(acc,4,4)
  const int bm = blockIdx.x, bn = blockIdx.y;
  gemm_core<128,128,2,2>(attnOut + (size_t)bm*128*1024, 1024,
                         woT + (size_t)bn*128*1024, 1024, 16, As, Bs, acc);
  const int tid=threadIdx.x, w=tid>>6, lane=tid&63, col=lane&15, quad=lane>>4;
  const int wr=w>>1, wc=w&1;
  #pragma unroll
  for(int i=0;i<4;++i){
    int row0 = bm*128 + wr*64 + i*16 + quad*4;
    #pragma unroll
    for(int j=0;j<4;++j){
      int c = bn*128 + wc*64 + j*16 + col;
      float bsv = bo[c];
      #pragma unroll
      for(int r=0;r<4;++r){
        size_t idx = (size_t)(row0+r)*1024 + c;
        y1[idx] = acc[i][j][r] + bsv + x[idx];
      }
    }
  }
}

// ---------------- FFN (row-quartered) ----------------
__global__ __launch_bounds__(256,2) void k_ffn1(const unsigned short* __restrict__ xb2,
    const unsigned short* __restrict__ w1T, const float* __restrict__ b1,
    unsigned short* __restrict__ hbuf, int rbase){
  __shared__ __align__(16) unsigned short As[128*64];
  __shared__ __align__(16) unsigned short Bs[128*64];
  facc4 acc[4][4]; ZERO_ACC(acc,4,4)
  const int bm = blockIdx.x, bn = blockIdx.y;      // 32 x 32
  gemm_core<128,128,2,2>(xb2 + ((size_t)(rbase*32 + bm))*131072, 1024,
                         w1T + (size_t)bn*128*1024, 1024, 16, As, Bs, acc);
  const int tid=threadIdx.x, w=tid>>6, lane=tid&63, col=lane&15, quad=lane>>4;
  const int wr=w>>1, wc=w&1;
  #pragma unroll
  for(int i=0;i<4;++i){
    int lrow0 = bm*128 + wr*64 + i*16 + quad*4;    // local row within quarter
    #pragma unroll
    for(int j=0;j<4;++j){
      int c = bn*128 + wc*64 + j*16 + col;
      float bsv = b1[c];
      #pragma unroll
      for(int r=0;r<4;++r){
        float v = acc[i][j][r] + bsv;
        float g = 0.5f*v*(1.0f+erff(v*0.70710678118654752f));   // exact GELU
        hbuf[(size_t)(lrow0+r)*4096 + c] = f2bf(g);
      }
    }
  }
}

__global__ __launch_bounds__(256,2) void k_ffn2(const unsigned short* __restrict__ hbuf,
    const unsigned short* __restrict__ w2T, const float* __restrict__ b2,
    const unsigned short* __restrict__ xb2, float* __restrict__ y2, int rbase){
  __shared__ __align__(16) unsigned short As[128*64];
  __shared__ __align__(16) unsigned short Bs[128*64];
  facc4 acc[4][4]; ZERO_ACC(acc,4,4)
  const int bm = blockIdx.x, bn = blockIdx.y;      // 32 x 8
  gemm_core<128,128,2,2>(hbuf + (size_t)bm*128*4096, 4096,
                         w2T + (size_t)bn*128*4096, 4096, 64, As, Bs, acc);
  const int tid=threadIdx.x, w=tid>>6, lane=tid&63, col=lane&15, quad=lane>>4;
  const int wr=w>>1, wc=w&1;
  #pragma unroll
  for(int i=0;i<4;++i){
    int grow0 = rbase*4096 + bm*128 + wr*64 + i*16 + quad*4;
    #pragma unroll
    for(int j=0;j<4;++j){
      int c = bn*128 + wc*64 + j*16 + col;
      float bsv = b2[c];
      #pragma unroll
      for(int r=0;r<4;++r){
        size_t idx = (size_t)(grow0+r)*1024 + c;
        y2[idx] = acc[i][j][r] + bsv + bf2f(xb2[idx]);   // residual = LN1 out (bf16)
      }
    }
  }
}

// ---------------- LayerNorm (fp32 in; fp32 and/or bf16 out) ----------------
__global__ __launch_bounds__(256) void k_ln(const float* __restrict__ in,
    const float* __restrict__ g, const float* __restrict__ b,
    float* __restrict__ outf, unsigned short* __restrict__ outb){
  __shared__ float rs[4], rs2[4];
  int row = blockIdx.x;
  const float* x = in + (size_t)row*1024;
  float s=0.f, s2=0.f;
  for(int i=threadIdx.x;i<1024;i+=256){ float v=x[i]; s+=v; s2+=v*v; }
  #pragma unroll
  for(int d=32;d;d>>=1){ s+=__shfl_down(s,d); s2+=__shfl_down(s2,d); }
  int w=threadIdx.x>>6, lane=threadIdx.x&63;
  if(lane==0){ rs[w]=s; rs2[w]=s2; }
  __syncthreads();
  float S=rs[0]+rs[1]+rs[2]+rs[3], S2=rs2[0]+rs2[1]+rs2[2]+rs2[3];
  float mu=S*(1.0f/1024.0f);
  float var=S2*(1.0f/1024.0f)-mu*mu;
  float rinv = rsqrtf(var+1e-5f);
  for(int i=threadIdx.x;i<1024;i+=256){
    float v=(x[i]-mu)*rinv*g[i]+b[i];
    if(outf) outf[(size_t)row*1024+i]=v;
    if(outb) outb[(size_t)row*1024+i]=f2bf(v);
  }
}

// ---------------- launch ----------------
extern "C" void kernel_launch(void* const* d_in, const int* in_sizes, int n_in,
                              void* d_out, int out_size, void* d_ws, size_t ws_size,
                              hipStream_t stream){
  const float* x   = (const float*)d_in[0];
  const float* wq  = (const float*)d_in[1];
  const float* bq  = (const float*)d_in[2];
  const float* wk  = (const float*)d_in[3];
  const float* bk  = (const float*)d_in[4];
  const float* wv  = (const float*)d_in[5];
  const float* bv  = (const float*)d_in[6];
  const float* wo  = (const float*)d_in[7];
  const float* bo  = (const float*)d_in[8];
  const float* proj= (const float*)d_in[9];
  const float* w1  = (const float*)d_in[10];
  const float* b1  = (const float*)d_in[11];
  const float* w2  = (const float*)d_in[12];
  const float* b2  = (const float*)d_in[13];
  const float* ln1g= (const float*)d_in[14];
  const float* ln1b= (const float*)d_in[15];
  const float* ln2g= (const float*)d_in[16];
  const float* ln2b= (const float*)d_in[17];
  (void)in_sizes; (void)n_in; (void)out_size;

  char* ws = (char*)d_ws;
  size_t off = 0;
  auto alloc = [&](size_t bytes)->char*{ char* p = ws + off; off += (bytes + 255) & ~(size_t)255; return p; };
  unsigned short* wqkvT = (unsigned short*)alloc(6291456);
  unsigned short* woT   = (unsigned short*)alloc(2097152);
  unsigned short* w1T   = (unsigned short*)alloc(8388608);
  unsigned short* w2T   = (unsigned short*)alloc(8388608);
  unsigned short* projB = (unsigned short*)alloc(32768);
  unsigned short* kvT   = (unsigned short*)alloc(2621440);
  float* pmax = (float*)alloc(16384);
  float* mxK  = (float*)alloc(256);
  // A1..A7 activation slabs with lifetime-based aliasing (total 246.6 MiB):
  char* A1 = alloc(33554432);   // xb -> Qp (per quarter) -> y1/y2 low half
  char* A2 = alloc(33554432);   // Qb -> y1/y2 high half (A1+A2 contiguous)
  char* A3 = alloc(33554432);   // Kb -> xb2
  char* A4 = alloc(41943040);   // Vt -> hbuf (per FFN quarter, 32 MiB used)
  char* A5 = alloc(33554432);   // KpT (per quarter)
  char* A6 = alloc(20971520);   // kv split-K partials (per quarter)
  char* A7 = alloc(33554432);   // attnOut (all heads)
  if (off > ws_size) return;    // ws too small -> clean absmax fail (diagnostic)

  unsigned short* xb   = (unsigned short*)A1;
  unsigned short* Qp   = (unsigned short*)A1;
  unsigned short* Qb   = (unsigned short*)A2;
  unsigned short* Kb   = (unsigned short*)A3;
  unsigned short* xb2  = (unsigned short*)A3;
  unsigned short* Vt   = (unsigned short*)A4;
  unsigned short* hbuf = (unsigned short*)A4;
  unsigned short* KpT  = (unsigned short*)A5;
  float*          kvpart = (float*)A6;
  unsigned short* attnOut = (unsigned short*)A7;
  float* y1 = (float*)A1;       // 64 MiB spanning A1+A2
  float* y2 = (float*)A1;       // in-place over y1 (read-then-write same idx)

  dim3 blk(256);
  k_transpose<<<dim3(32,32),blk,0,stream>>>(wq, wqkvT,               1024, 1024);
  k_transpose<<<dim3(32,32),blk,0,stream>>>(wk, wqkvT+1024ull*1024,  1024, 1024);
  k_transpose<<<dim3(32,32),blk,0,stream>>>(wv, wqkvT+2048ull*1024,  1024, 1024);
  k_transpose<<<dim3(32,32),blk,0,stream>>>(wo, woT,                 1024, 1024);
  k_transpose<<<dim3(128,32),blk,0,stream>>>(w1, w1T,                1024, 4096);
  k_transpose<<<dim3(32,128),blk,0,stream>>>(w2, w2T,                4096, 1024);
  k_cvt<<<65536,blk,0,stream>>>(x, xb, 16777216);
  k_cvt<<<64,blk,0,stream>>>(proj, projB, 16384);
  k_vones<<<1024,blk,0,stream>>>(Vt);

  k_qkv<<<dim3(128,24),blk,0,stream>>>(xb, wqkvT, bq, bk, bv, Qb, Kb, Vt);
  k_featk_max<<<4096,blk,0,stream>>>(Kb, projB, pmax);
  k_mxk<<<1,64,0,stream>>>(pmax, mxK);

  for (int q = 0; q < 4; ++q) {
    k_featq<<<1024,blk,0,stream>>>(Qb, projB, Qp, q);
    k_featk<<<1024,blk,0,stream>>>(Kb, projB, mxK, KpT, q);
    k_kv<<<dim3(16,16),blk,0,stream>>>(KpT, Vt, kvpart, q);
    k_kvred<<<1280,blk,0,stream>>>(kvpart, kvT, q);
    k_attn<<<dim3(32,16),blk,0,stream>>>(Qp, kvT, attnOut, q);
  }

  k_oproj<<<dim3(128,8),blk,0,stream>>>(attnOut, woT, bo, x, y1);
  k_ln<<<16384,blk,0,stream>>>(y1, ln1g, ln1b, nullptr, xb2);

  for (int r = 0; r < 4; ++r) {
    k_ffn1<<<dim3(32,32),blk,0,stream>>>(xb2, w1T, b1, hbuf, r);
    k_ffn2<<<dim3(32,8),blk,0,stream>>>(hbuf, w2T, b2, xb2, y2, r);
  }
  k_ln<<<16384,blk,0,stream>>>(y2, ln2g, ln2b, (float*)d_out, nullptr);
}

// Round 3
// 1054.124 us; speedup vs baseline: 1.2290x; 1.2290x over previous
//
#include <hip/hip_runtime.h>
#include <math.h>

#define DEV __device__ __forceinline__

typedef __attribute__((ext_vector_type(8))) short frag8;     // 8 x bf16 (4 VGPRs)
typedef __attribute__((ext_vector_type(4))) float facc4;     // MFMA accumulator
typedef __attribute__((ext_vector_type(4))) unsigned short us4;
typedef __attribute__((ext_vector_type(8))) unsigned short us8;

DEV float bf2f(unsigned short u){ union{unsigned i; float f;} x; x.i=((unsigned)u)<<16; return x.f; }
DEV unsigned short f2bf(float f){ union{float f; unsigned i;} x; x.f=f;
  return (unsigned short)((x.i + 0x7FFFu + ((x.i>>16)&1u))>>16); }

// direct global->LDS DMA, 16B per lane. LDS dest is wave-uniform base + lane*16.
#define GLD16(g, l) __builtin_amdgcn_global_load_lds( \
    (const __attribute__((address_space(1))) void*)(g), \
    (__attribute__((address_space(3))) void*)(l), 16, 0, 0)

// Stage a ROWSx64 bf16 tile (K-major rows, ld elements) into LDS with XOR-8
// chunk swizzle: LDS chunk (r,cg) holds global chunk (r, cg^(r&7)).
template<int ROWS>
DEV void stage_tile(const unsigned short* __restrict__ g0, int ld, unsigned short* s0){
  static_assert(ROWS % 8 == 0, "");
  constexpr int SLOTS = ROWS/8;
  const int w = threadIdx.x>>6, lane = threadIdx.x&63;
  for (int s = w; s < SLOTS; s += 4) {
    int c  = (s<<6) + lane;
    int r  = c >> 3, cg = c & 7;
    int kg = cg ^ (r & 7);
    GLD16(g0 + (size_t)r*ld + (kg<<3), s0 + (s<<9));
  }
}

DEV frag8 frag_ld(const unsigned short* s, int row, int kg){
  int cg = kg ^ (row & 7);
  return *(const frag8*)(s + (row<<6) + (cg<<3));
}

// C[BM][BN] += A[BM][K] * Bt[BN][K]^T, K consumed in kIters chunks of 64.
template<int BM, int BN, int WR, int WC>
DEV void gemm_core(const unsigned short* __restrict__ Ag, int lda,
                   const unsigned short* __restrict__ Bg, int ldb,
                   int kIters, unsigned short* As, unsigned short* Bs,
                   facc4 (&acc)[BM/(WR*16)][BN/(WC*16)]) {
  constexpr int WM = BM/(WR*16), WN = BN/(WC*16);
  const int tid = threadIdx.x, w = tid>>6, lane = tid&63;
  const int wr = w / WC, wc = w % WC;
  const int col = lane & 15, quad = lane >> 4;
  for (int kt = 0; kt < kIters; ++kt) {
    stage_tile<BM>(Ag + kt*64, lda, As);
    stage_tile<BN>(Bg + kt*64, ldb, Bs);
    __syncthreads();
    #pragma unroll
    for (int ks = 0; ks < 2; ++ks) {
      frag8 af[WM], bfr[WN];
      #pragma unroll
      for (int i=0;i<WM;++i) af[i]  = frag_ld(As, wr*WM*16 + i*16 + col, ks*4+quad);
      #pragma unroll
      for (int j=0;j<WN;++j) bfr[j] = frag_ld(Bs, wc*WN*16 + j*16 + col, ks*4+quad);
      #pragma unroll
      for (int i=0;i<WM;++i)
        #pragma unroll
        for (int j=0;j<WN;++j)
          acc[i][j] = __builtin_amdgcn_mfma_f32_16x16x32_bf16(af[i], bfr[j], acc[i][j], 0,0,0);
    }
    __syncthreads();
  }
}

#define ZERO_ACC(acc, I, J) { facc4 zz = {0.f,0.f,0.f,0.f}; \
  _Pragma("unroll") for(int i_=0;i_<I;++i_) _Pragma("unroll") for(int j_=0;j_<J;++j_) acc[i_][j_]=zz; }

// ---------------- prep kernels ----------------
// 64x64 tile transpose: in[K][N] fp32 -> out[N][K] bf16. float4 loads, us4 stores.
DEV void tr64(const float* __restrict__ in, unsigned short* __restrict__ out, int K, int N){
  __shared__ float t[64][65];
  const int bx = blockIdx.x*64, by = blockIdx.y*64;
  const int tid = threadIdx.x;
  const int r0 = tid>>4, c4 = (tid&15)*4;
  #pragma unroll
  for(int it=0; it<4; ++it){
    int r = r0 + it*16;
    float4 v = *(const float4*)(in + (size_t)(by+r)*N + bx + c4);
    t[r][c4+0]=v.x; t[r][c4+1]=v.y; t[r][c4+2]=v.z; t[r][c4+3]=v.w;
  }
  __syncthreads();
  #pragma unroll
  for(int it=0; it<4; ++it){
    int n = r0 + it*16;                     // original col
    us4 o;
    #pragma unroll
    for(int e=0;e<4;++e) o[e] = f2bf(t[c4+e][n]);
    *(us4*)(out + (size_t)(bx+n)*K + by + c4) = o;
  }
}

__global__ void k_transpose4(const float* __restrict__ wq, const float* __restrict__ wk,
                             const float* __restrict__ wv, const float* __restrict__ wo,
                             unsigned short* __restrict__ wqkvT, unsigned short* __restrict__ woT){
  const float* in; unsigned short* out;
  int z = blockIdx.z;
  if(z==0){in=wq; out=wqkvT;} else if(z==1){in=wk; out=wqkvT+1048576;}
  else if(z==2){in=wv; out=wqkvT+2097152;} else {in=wo; out=woT;}
  tr64(in, out, 1024, 1024);
}

__global__ void k_transpose(const float* __restrict__ in, unsigned short* __restrict__ out,
                            int K, int N){ tr64(in, out, K, N); }

__global__ void k_cvt4(const float* __restrict__ in, unsigned short* __restrict__ out, int n4){
  int i = blockIdx.x*256 + threadIdx.x;
  if(i<n4){ float4 v = ((const float4*)in)[i];
    us4 o = {f2bf(v.x),f2bf(v.y),f2bf(v.z),f2bf(v.w)};
    ((us4*)out)[i]=o; }
}

__global__ void k_vones(unsigned short* __restrict__ Vt){  // Vt row 64 = 1.0 per head
  int i = blockIdx.x*256+threadIdx.x;       // 64*4096
  int head=i>>12, n=i&4095;
  Vt[((size_t)head*80+64)*4096 + n] = 0x3F80;
}

// ---------------- QKV projection ----------------
__global__ __launch_bounds__(256,2) void k_qkv(const unsigned short* __restrict__ xb,
    const unsigned short* __restrict__ wqkvT,
    const float* __restrict__ bq, const float* __restrict__ bk, const float* __restrict__ bv,
    unsigned short* __restrict__ Qb, unsigned short* __restrict__ Kb, unsigned short* __restrict__ Vt){
  __shared__ __align__(16) unsigned short As[128*64];
  __shared__ __align__(16) unsigned short Bs[128*64];
  facc4 acc[4][4]; ZERO_ACC(acc,4,4)
  const int bm = blockIdx.x, bn = blockIdx.y;
  gemm_core<128,128,2,2>(xb + (size_t)bm*128*1024, 1024,
                         wqkvT + (size_t)bn*128*1024, 1024, 16, As, Bs, acc);
  const int tid=threadIdx.x, w=tid>>6, lane=tid&63, col=lane&15, quad=lane>>4;
  const int wr=w>>1, wc=w&1;
  #pragma unroll
  for(int i=0;i<4;++i){
    int row0 = bm*128 + wr*64 + i*16 + quad*4;
    int bb = row0 >> 12, n0 = row0 & 4095;
    #pragma unroll
    for(int j=0;j<4;++j){
      int c = bn*128 + wc*64 + j*16 + col;
      int region = c >> 10, f = c & 1023, he = f >> 6, hd = f & 63;
      const float* bias = (region==0)? bq : (region==1)? bk : bv;
      float bsv = bias[f];
      if(region < 2){
        unsigned short* dst = (region==0? Qb : Kb) + ((size_t)(bb*16+he)*4096 + n0)*64 + hd;
        #pragma unroll
        for(int r=0;r<4;++r) dst[(size_t)r*64] = f2bf(acc[i][j][r] + bsv);
      } else {
        us4 pk;
        #pragma unroll
        for(int r=0;r<4;++r) pk[r] = f2bf(acc[i][j][r] + bsv);
        *(us4*)(Vt + ((size_t)(bb*16+he)*80 + hd)*4096 + n0) = pk;
      }
    }
  }
}

// ---------------- FAVOR+ features (per head-quarter of 16 heads) ----------------
__global__ __launch_bounds__(256,2) void k_featq(const unsigned short* __restrict__ Qb,
    const unsigned short* __restrict__ projB, unsigned short* __restrict__ Qp, int qbase){
  __shared__ __align__(16) unsigned short As[64*64];
  __shared__ __align__(16) unsigned short Bs[256*64];
  __shared__ float diagS[64];
  facc4 acc[1][16]; ZERO_ACC(acc,1,16)
  const int br = blockIdx.x;                       // 1024 blocks = 16 heads * 64
  gemm_core<64,256,4,1>(Qb + ((size_t)(qbase*1024 + br))*4096, 64, projB, 64, 1, As, Bs, acc);
  if (threadIdx.x < 64){
    int t=threadIdx.x; float ss=0.f;
    #pragma unroll
    for(int kg=0;kg<8;++kg){ int cg=kg^(t&7); const unsigned short* p = As + t*64 + cg*8;
      #pragma unroll
      for(int e=0;e<8;++e){ float v=bf2f(p[e]); ss+=v*v; } }
    diagS[t]=0.0625f*ss;                            // 0.5 * dn^2
  }
  __syncthreads();
  const int w=threadIdx.x>>6, lane=threadIdx.x&63, col=lane&15, quad=lane>>4;
  const float dn=0.35355339059327378f;
  float mx[4];
  #pragma unroll
  for(int r=0;r<4;++r){ float m=-1e30f;
    #pragma unroll
    for(int j=0;j<16;++j) m=fmaxf(m, acc[0][j][r]);
    #pragma unroll
    for(int d=1; d<16; d<<=1) m=fmaxf(m, __shfl_xor(m,d));
    mx[r]=m*dn;
  }
  size_t tok0 = (size_t)br*64;
  #pragma unroll
  for(int j=0;j<16;++j){
    #pragma unroll
    for(int r=0;r<4;++r){
      int t = w*16 + quad*4 + r;
      float dd = dn*acc[0][j][r];
      Qp[(tok0 + t)*256 + j*16 + col] = f2bf(0.0625f*(expf(dd - diagS[t] - mx[r]) + 1e-4f));
    }
  }
}

__global__ __launch_bounds__(256,2) void k_featk_max(const unsigned short* __restrict__ Kb,
    const unsigned short* __restrict__ projB, float* __restrict__ pmax){
  __shared__ __align__(16) unsigned short As[64*64];
  __shared__ __align__(16) unsigned short Bs[256*64];
  __shared__ float wm[4];
  facc4 acc[1][16]; ZERO_ACC(acc,1,16)
  const int br = blockIdx.x;                       // 4096 (all heads)
  gemm_core<64,256,4,1>(Kb + (size_t)br*64*64, 64, projB, 64, 1, As, Bs, acc);
  const int w=threadIdx.x>>6, lane=threadIdx.x&63;
  float m=-1e30f;
  #pragma unroll
  for(int j=0;j<16;++j)
    #pragma unroll
    for(int r=0;r<4;++r) m=fmaxf(m, acc[0][j][r]);
  #pragma unroll
  for(int d=1; d<64; d<<=1) m=fmaxf(m, __shfl_xor(m,d));
  if(lane==0) wm[w]=m;
  __syncthreads();
  if(threadIdx.x==0)
    pmax[br] = fmaxf(fmaxf(wm[0],wm[1]),fmaxf(wm[2],wm[3])) * 0.35355339059327378f;
}

__global__ void k_mxk(const float* __restrict__ pmax, float* __restrict__ mxK){
  int h = threadIdx.x;  // 64
  float m=-1e30f;
  for(int i=0;i<64;++i) m=fmaxf(m, pmax[h*64+i]);
  mxK[h]=m;
}

__global__ __launch_bounds__(256,2) void k_featk(const unsigned short* __restrict__ Kb,
    const unsigned short* __restrict__ projB, const float* __restrict__ mxK,
    unsigned short* __restrict__ KpT, int qbase){
  __shared__ __align__(16) unsigned short As[64*64];
  __shared__ __align__(16) unsigned short Bs[256*64];
  __shared__ float diagS[64];
  facc4 acc[1][16]; ZERO_ACC(acc,1,16)
  const int br = blockIdx.x;                       // 1024
  gemm_core<64,256,4,1>(Kb + ((size_t)(qbase*1024 + br))*4096, 64, projB, 64, 1, As, Bs, acc);
  if (threadIdx.x < 64){
    int t=threadIdx.x; float ss=0.f;
    #pragma unroll
    for(int kg=0;kg<8;++kg){ int cg=kg^(t&7); const unsigned short* p = As + t*64 + cg*8;
      #pragma unroll
      for(int e=0;e<8;++e){ float v=bf2f(p[e]); ss+=v*v; } }
    diagS[t]=0.0625f*ss;
  }
  __syncthreads();
  const int lh = br >> 6;
  const float mxh = mxK[qbase*16 + lh];
  const int w=threadIdx.x>>6, lane=threadIdx.x&63, col=lane&15, quad=lane>>4;
  const int n0 = (br&63)*64 + w*16 + quad*4;
  const float dn=0.35355339059327378f;
  #pragma unroll
  for(int j=0;j<16;++j){
    us4 pk;
    #pragma unroll
    for(int r=0;r<4;++r){
      int t = w*16 + quad*4 + r;
      float dd = dn*acc[0][j][r];
      pk[r] = f2bf(0.0625f*(expf(dd - diagS[t] - mxh) + 1e-4f));
    }
    *(us4*)(KpT + ((size_t)lh*256 + j*16 + col)*4096 + n0) = pk;  // [M][N] transposed
  }
}

// ---------------- kv = Kp^T V (split-K 16 over tokens), +ones row ----------------
__global__ __launch_bounds__(256,2) void k_kv(const unsigned short* __restrict__ KpT,
    const unsigned short* __restrict__ Vt, float* __restrict__ part, int qbase){
  __shared__ __align__(16) unsigned short As[256*64];
  __shared__ __align__(16) unsigned short Bs[80*64];
  facc4 acc[4][5]; ZERO_ACC(acc,4,5)
  const int ksp = blockIdx.x, lh = blockIdx.y;     // 16 x 16
  gemm_core<256,80,4,1>(KpT + (size_t)lh*1048576 + ksp*256, 4096,
                        Vt  + ((size_t)(qbase*16+lh))*327680 + ksp*256, 4096, 4, As, Bs, acc);
  const int w=threadIdx.x>>6, lane=threadIdx.x&63, col=lane&15, quad=lane>>4;
  #pragma unroll
  for(int i=0;i<4;++i){
    int mp0 = w*64 + i*16 + quad*4;
    #pragma unroll
    for(int j=0;j<5;++j){
      int d = j*16+col;
      *(facc4*)(part + (((size_t)(ksp*16 + lh))*80 + d)*256 + mp0) = acc[i][j];
    }
  }
}

__global__ void k_kvred(const float* __restrict__ part, unsigned short* __restrict__ kvT, int qbase){
  int i = blockIdx.x*256 + threadIdx.x;            // 16*80*256 = 327680
  float s=0.f;
  #pragma unroll
  for(int ks=0;ks<16;++ks) s += part[(size_t)ks*327680 + i];
  kvT[(size_t)qbase*327680 + i] = f2bf(s);
}

// ---------------- attn = Qp kv / (Qp s) ----------------
__global__ __launch_bounds__(256,2) void k_attn(const unsigned short* __restrict__ Qp,
    const unsigned short* __restrict__ kvT, unsigned short* __restrict__ attnOut, int qbase){
  __shared__ __align__(16) unsigned short As[128*64];
  __shared__ __align__(16) unsigned short Bs[80*64];
  facc4 acc[2][5]; ZERO_ACC(acc,2,5)
  const int mb = blockIdx.x, lh = blockIdx.y;      // 32 x 16
  gemm_core<128,80,4,1>(Qp  + (size_t)lh*1048576 + (size_t)mb*32768, 256,
                        kvT + ((size_t)(qbase*16+lh))*20480, 256, 4, As, Bs, acc);
  const int w=threadIdx.x>>6, lane=threadIdx.x&63, col=lane&15, quad=lane>>4;
  const int gh = qbase*16 + lh, b = gh>>4, h = gh&15;
  #pragma unroll
  for(int i=0;i<2;++i){
    #pragma unroll
    for(int r=0;r<4;++r){
      float den = __shfl(acc[i][4][r], lane & 48); // col 64 for this quad's rows
      float inv = 1.0f/den;
      int n = mb*128 + w*32 + i*16 + quad*4 + r;
      size_t base = ((size_t)(b*4096 + n))*1024 + h*64;
      #pragma unroll
      for(int j=0;j<4;++j)
        attnOut[base + j*16 + col] = f2bf(acc[i][j][r]*inv);
    }
  }
}

// ---------------- output projection + residual (y1 bf16) ----------------
__global__ __launch_bounds__(256,2) void k_oproj(const unsigned short* __restrict__ attnOut,
    const unsigned short* __restrict__ woT, const float* __restrict__ bo,
    const float* __restrict__ x, unsigned short* __restrict__ y1){
  __shared__ __align__(16) unsigned short As[128*64];
  __shared__ __align__(16) unsigned short Bs[128*64];
  facc4 acc[4][4]; ZERO_ACC(acc,4,4)
  const int bm = blockIdx.x, bn = blockIdx.y;
  gemm_core<128,128,2,2>(attnOut + (size_t)bm*128*1024, 1024,
                         woT + (size_t)bn*128*1024, 1024, 16, As, Bs, acc);
  const int tid=threadIdx.x, w=tid>>6, lane=tid&63, col=lane&15, quad=lane>>4;
  const int wr=w>>1, wc=w&1;
  #pragma unroll
  for(int i=0;i<4;++i){
    int row0 = bm*128 + wr*64 + i*16 + quad*4;
    #pragma unroll
    for(int j=0;j<4;++j){
      int c = bn*128 + wc*64 + j*16 + col;
      float bsv = bo[c];
      #pragma unroll
      for(int r=0;r<4;++r){
        size_t idx = (size_t)(row0+r)*1024 + c;
        y1[idx] = f2bf(acc[i][j][r] + bsv + x[idx]);
      }
    }
  }
}

// ---------------- FFN (halved) ----------------
__global__ __launch_bounds__(256,2) void k_ffn1(const unsigned short* __restrict__ xb2,
    const unsigned short* __restrict__ w1T, const float* __restrict__ b1,
    unsigned short* __restrict__ hbuf, int hbase){
  __shared__ __align__(16) unsigned short As[128*64];
  __shared__ __align__(16) unsigned short Bs[128*64];
  facc4 acc[4][4]; ZERO_ACC(acc,4,4)
  const int bm = blockIdx.x, bn = blockIdx.y;      // 64 x 32
  gemm_core<128,128,2,2>(xb2 + ((size_t)(hbase*64 + bm))*131072, 1024,
                         w1T + (size_t)bn*128*1024, 1024, 16, As, Bs, acc);
  const int tid=threadIdx.x, w=tid>>6, lane=tid&63, col=lane&15, quad=lane>>4;
  const int wr=w>>1, wc=w&1;
  #pragma unroll
  for(int i=0;i<4;++i){
    int lrow0 = bm*128 + wr*64 + i*16 + quad*4;    // local row within half
    #pragma unroll
    for(int j=0;j<4;++j){
      int c = bn*128 + wc*64 + j*16 + col;
      float bsv = b1[c];
      #pragma unroll
      for(int r=0;r<4;++r){
        float v = acc[i][j][r] + bsv;
        float g = 0.5f*v*(1.0f+erff(v*0.70710678118654752f));   // exact GELU
        hbuf[(size_t)(lrow0+r)*4096 + c] = f2bf(g);
      }
    }
  }
}

__global__ __launch_bounds__(256,2) void k_ffn2(const unsigned short* __restrict__ hbuf,
    const unsigned short* __restrict__ w2T, const float* __restrict__ b2,
    const unsigned short* __restrict__ xb2, unsigned short* __restrict__ y2, int hbase){
  __shared__ __align__(16) unsigned short As[128*64];
  __shared__ __align__(16) unsigned short Bs[128*64];
  facc4 acc[4][4]; ZERO_ACC(acc,4,4)
  const int bm = blockIdx.x, bn = blockIdx.y;      // 64 x 8
  gemm_core<128,128,2,2>(hbuf + (size_t)bm*128*4096, 4096,
                         w2T + (size_t)bn*128*4096, 4096, 64, As, Bs, acc);
  const int tid=threadIdx.x, w=tid>>6, lane=tid&63, col=lane&15, quad=lane>>4;
  const int wr=w>>1, wc=w&1;
  #pragma unroll
  for(int i=0;i<4;++i){
    int grow0 = hbase*8192 + bm*128 + wr*64 + i*16 + quad*4;
    #pragma unroll
    for(int j=0;j<4;++j){
      int c = bn*128 + wc*64 + j*16 + col;
      float bsv = b2[c];
      #pragma unroll
      for(int r=0;r<4;++r){
        size_t idx = (size_t)(grow0+r)*1024 + c;
        y2[idx] = f2bf(acc[i][j][r] + bsv + bf2f(xb2[idx]));   // residual = LN1 out
      }
    }
  }
}

// ---------------- LayerNorm: bf16 in, wave-per-row, fp32 and/or bf16 out ------
__global__ __launch_bounds__(256) void k_lnb(const unsigned short* __restrict__ in,
    const float* __restrict__ g, const float* __restrict__ b,
    float* __restrict__ outf, unsigned short* __restrict__ outb){
  const int row = blockIdx.x*4 + (threadIdx.x>>6);
  const int lane = threadIdx.x&63;
  const unsigned short* x = in + (size_t)row*1024 + lane*16;
  float v[16];
  float s=0.f, s2=0.f;
  #pragma unroll
  for(int q=0;q<2;++q){ us8 u = *(const us8*)(x + q*8);
    #pragma unroll
    for(int e=0;e<8;++e){ float f=bf2f(u[e]); v[q*8+e]=f; s+=f; s2+=f*f; } }
  #pragma unroll
  for(int d=32;d;d>>=1){ s+=__shfl_xor(s,d); s2+=__shfl_xor(s2,d); }
  float mu = s*(1.0f/1024.0f), var = s2*(1.0f/1024.0f)-mu*mu;
  float rinv = rsqrtf(var+1e-5f);
  const int cb = lane*16;
  if(outf){
    #pragma unroll
    for(int q=0;q<4;++q){
      float4 o;
      o.x=(v[q*4+0]-mu)*rinv*g[cb+q*4+0]+b[cb+q*4+0];
      o.y=(v[q*4+1]-mu)*rinv*g[cb+q*4+1]+b[cb+q*4+1];
      o.z=(v[q*4+2]-mu)*rinv*g[cb+q*4+2]+b[cb+q*4+2];
      o.w=(v[q*4+3]-mu)*rinv*g[cb+q*4+3]+b[cb+q*4+3];
      *(float4*)(outf + (size_t)row*1024 + cb + q*4) = o;
    }
  }
  if(outb){
    #pragma unroll
    for(int q=0;q<2;++q){
      us8 o;
      #pragma unroll
      for(int e=0;e<8;++e) o[e]=f2bf((v[q*8+e]-mu)*rinv*g[cb+q*8+e]+b[cb+q*8+e]);
      *(us8*)(outb + (size_t)row*1024 + cb + q*8) = o;
    }
  }
}

// ---------------- launch ----------------
extern "C" void kernel_launch(void* const* d_in, const int* in_sizes, int n_in,
                              void* d_out, int out_size, void* d_ws, size_t ws_size,
                              hipStream_t stream){
  const float* x   = (const float*)d_in[0];
  const float* wq  = (const float*)d_in[1];
  const float* bq  = (const float*)d_in[2];
  const float* wk  = (const float*)d_in[3];
  const float* bk  = (const float*)d_in[4];
  const float* wv  = (const float*)d_in[5];
  const float* bv  = (const float*)d_in[6];
  const float* wo  = (const float*)d_in[7];
  const float* bo  = (const float*)d_in[8];
  const float* proj= (const float*)d_in[9];
  const float* w1  = (const float*)d_in[10];
  const float* b1  = (const float*)d_in[11];
  const float* w2  = (const float*)d_in[12];
  const float* b2  = (const float*)d_in[13];
  const float* ln1g= (const float*)d_in[14];
  const float* ln1b= (const float*)d_in[15];
  const float* ln2g= (const float*)d_in[16];
  const float* ln2b= (const float*)d_in[17];
  (void)in_sizes; (void)n_in; (void)out_size;

  char* ws = (char*)d_ws;
  size_t off = 0;
  auto alloc = [&](size_t bytes)->char*{ char* p = ws + off; off += (bytes + 255) & ~(size_t)255; return p; };
  unsigned short* wqkvT = (unsigned short*)alloc(6291456);
  unsigned short* woT   = (unsigned short*)alloc(2097152);
  unsigned short* w1T   = (unsigned short*)alloc(8388608);
  unsigned short* w2T   = (unsigned short*)alloc(8388608);
  unsigned short* projB = (unsigned short*)alloc(32768);
  unsigned short* kvT   = (unsigned short*)alloc(2621440);
  float* pmax = (float*)alloc(16384);
  float* mxK  = (float*)alloc(256);
  // Single 220 MiB region, lifetime-overlaid:
  //  [0,32)    xb -> Qp(quarter) -> y1(bf16)
  //  [32,64)   Qb -> xb2
  //  [64,128)  Kb(64..96) + Vt(96..136 partial) -> hbuf (FFN half, 64 MiB)
  //  [96,136)  Vt
  //  [136,168) KpT(quarter)
  //  [168,188) kv split-K partials
  //  [188,220) attnOut -> y2(bf16)
  char* R = alloc(230686720ull);
  if (off > ws_size) return;    // ws too small -> clean absmax fail (diagnostic)

  unsigned short* xb   = (unsigned short*)R;
  unsigned short* Qp   = (unsigned short*)R;
  unsigned short* y1   = (unsigned short*)R;
  unsigned short* Qb   = (unsigned short*)(R + 33554432);
  unsigned short* xb2  = (unsigned short*)(R + 33554432);
  unsigned short* Kb   = (unsigned short*)(R + 67108864);
  unsigned short* hbuf = (unsigned short*)(R + 67108864);
  unsigned short* Vt   = (unsigned short*)(R + 100663296);
  unsigned short* KpT  = (unsigned short*)(R + 142606336);
  float*          kvpart = (float*)(R + 176160768);
  unsigned short* attnOut = (unsigned short*)(R + 197132288);
  unsigned short* y2   = (unsigned short*)(R + 197132288);

  dim3 blk(256);
  k_transpose4<<<dim3(16,16,4),blk,0,stream>>>(wq, wk, wv, wo, wqkvT, woT);
  k_transpose<<<dim3(64,16),blk,0,stream>>>(w1, w1T, 1024, 4096);
  k_transpose<<<dim3(16,64),blk,0,stream>>>(w2, w2T, 4096, 1024);
  k_cvt4<<<16384,blk,0,stream>>>(x, xb, 4194304);
  k_cvt4<<<16,blk,0,stream>>>(proj, projB, 4096);
  k_vones<<<1024,blk,0,stream>>>(Vt);

  k_qkv<<<dim3(128,24),blk,0,stream>>>(xb, wqkvT, bq, bk, bv, Qb, Kb, Vt);
  k_featk_max<<<4096,blk,0,stream>>>(Kb, projB, pmax);
  k_mxk<<<1,64,0,stream>>>(pmax, mxK);

  for (int q = 0; q < 4; ++q) {
    k_featq<<<1024,blk,0,stream>>>(Qb, projB, Qp, q);
    k_featk<<<1024,blk,0,stream>>>(Kb, projB, mxK, KpT, q);
    k_kv<<<dim3(16,16),blk,0,stream>>>(KpT, Vt, kvpart, q);
    k_kvred<<<1280,blk,0,stream>>>(kvpart, kvT, q);
    k_attn<<<dim3(32,16),blk,0,stream>>>(Qp, kvT, attnOut, q);
  }

  k_oproj<<<dim3(128,8),blk,0,stream>>>(attnOut, woT, bo, x, y1);
  k_lnb<<<4096,blk,0,stream>>>(y1, ln1g, ln1b, nullptr, xb2);

  for (int h = 0; h < 2; ++h) {
    k_ffn1<<<dim3(64,32),blk,0,stream>>>(xb2, w1T, b1, hbuf, h);
    k_ffn2<<<dim3(64,8),blk,0,stream>>>(hbuf, w2T, b2, xb2, y2, h);
  }
  k_lnb<<<4096,blk,0,stream>>>(y2, ln2g, ln2b, (float*)d_out, nullptr);
}

// Round 4
// 1008.848 us; speedup vs baseline: 1.2841x; 1.0449x over previous
//
#include <hip/hip_runtime.h>
#include <math.h>

#define DEV __device__ __forceinline__

typedef __attribute__((ext_vector_type(8))) short frag8;     // 8 x bf16 (4 VGPRs)
typedef __attribute__((ext_vector_type(4))) float facc4;     // MFMA accumulator
typedef __attribute__((ext_vector_type(4))) unsigned short us4;
typedef __attribute__((ext_vector_type(8))) unsigned short us8;

DEV float bf2f(unsigned short u){ union{unsigned i; float f;} x; x.i=((unsigned)u)<<16; return x.f; }
DEV unsigned short f2bf(float f){ union{float f; unsigned i;} x; x.f=f;
  return (unsigned short)((x.i + 0x7FFFu + ((x.i>>16)&1u))>>16); }

// direct global->LDS DMA, 16B per lane. LDS dest is wave-uniform base + lane*16.
#define GLD16(g, l) __builtin_amdgcn_global_load_lds( \
    (const __attribute__((address_space(1))) void*)(g), \
    (__attribute__((address_space(3))) void*)(l), 16, 0, 0)

// Stage a ROWSx64 bf16 tile (K-major rows, ld elements) into LDS with XOR-8
// chunk swizzle: LDS chunk (r,cg) holds global chunk (r, cg^(r&7)).
template<int ROWS>
DEV void stage_tile(const unsigned short* __restrict__ g0, int ld, unsigned short* s0){
  static_assert(ROWS % 8 == 0, "");
  constexpr int SLOTS = ROWS/8;
  const int w = threadIdx.x>>6, lane = threadIdx.x&63;
  for (int s = w; s < SLOTS; s += 4) {
    int c  = (s<<6) + lane;
    int r  = c >> 3, cg = c & 7;
    int kg = cg ^ (r & 7);
    GLD16(g0 + (size_t)r*ld + (kg<<3), s0 + (s<<9));
  }
}

DEV frag8 frag_ld(const unsigned short* s, int row, int kg){
  int cg = kg ^ (row & 7);
  return *(const frag8*)(s + (row<<6) + (cg<<3));
}

// C[BM][BN] += A[BM][K] * Bt[BN][K]^T, K consumed in kIters chunks of 64.
template<int BM, int BN, int WR, int WC>
DEV void gemm_core(const unsigned short* __restrict__ Ag, int lda,
                   const unsigned short* __restrict__ Bg, int ldb,
                   int kIters, unsigned short* As, unsigned short* Bs,
                   facc4 (&acc)[BM/(WR*16)][BN/(WC*16)]) {
  constexpr int WM = BM/(WR*16), WN = BN/(WC*16);
  const int tid = threadIdx.x, w = tid>>6, lane = tid&63;
  const int wr = w / WC, wc = w % WC;
  const int col = lane & 15, quad = lane >> 4;
  for (int kt = 0; kt < kIters; ++kt) {
    stage_tile<BM>(Ag + kt*64, lda, As);
    stage_tile<BN>(Bg + kt*64, ldb, Bs);
    __syncthreads();
    #pragma unroll
    for (int ks = 0; ks < 2; ++ks) {
      frag8 af[WM], bfr[WN];
      #pragma unroll
      for (int i=0;i<WM;++i) af[i]  = frag_ld(As, wr*WM*16 + i*16 + col, ks*4+quad);
      #pragma unroll
      for (int j=0;j<WN;++j) bfr[j] = frag_ld(Bs, wc*WN*16 + j*16 + col, ks*4+quad);
      #pragma unroll
      for (int i=0;i<WM;++i)
        #pragma unroll
        for (int j=0;j<WN;++j)
          acc[i][j] = __builtin_amdgcn_mfma_f32_16x16x32_bf16(af[i], bfr[j], acc[i][j], 0,0,0);
    }
    __syncthreads();
  }
}

#define ZERO_ACC(acc, I, J) { facc4 zz = {0.f,0.f,0.f,0.f}; \
  _Pragma("unroll") for(int i_=0;i_<I;++i_) _Pragma("unroll") for(int j_=0;j_<J;++j_) acc[i_][j_]=zz; }

// ---------------- prep kernels ----------------
DEV void tr64(const float* __restrict__ in, unsigned short* __restrict__ out, int K, int N){
  __shared__ float t[64][65];
  const int bx = blockIdx.x*64, by = blockIdx.y*64;
  const int tid = threadIdx.x;
  const int r0 = tid>>4, c4 = (tid&15)*4;
  #pragma unroll
  for(int it=0; it<4; ++it){
    int r = r0 + it*16;
    float4 v = *(const float4*)(in + (size_t)(by+r)*N + bx + c4);
    t[r][c4+0]=v.x; t[r][c4+1]=v.y; t[r][c4+2]=v.z; t[r][c4+3]=v.w;
  }
  __syncthreads();
  #pragma unroll
  for(int it=0; it<4; ++it){
    int n = r0 + it*16;
    us4 o;
    #pragma unroll
    for(int e=0;e<4;++e) o[e] = f2bf(t[c4+e][n]);
    *(us4*)(out + (size_t)(bx+n)*K + by + c4) = o;
  }
}

__global__ void k_transpose4(const float* __restrict__ wq, const float* __restrict__ wk,
                             const float* __restrict__ wv, const float* __restrict__ wo,
                             unsigned short* __restrict__ wqkvT, unsigned short* __restrict__ woT){
  const float* in; unsigned short* out;
  int z = blockIdx.z;
  if(z==0){in=wq; out=wqkvT;} else if(z==1){in=wk; out=wqkvT+1048576;}
  else if(z==2){in=wv; out=wqkvT+2097152;} else {in=wo; out=woT;}
  tr64(in, out, 1024, 1024);
}

__global__ void k_transpose(const float* __restrict__ in, unsigned short* __restrict__ out,
                            int K, int N){ tr64(in, out, K, N); }

// merged: x->bf16 cvt (16384 blocks) | proj cvt (16 blocks) | Vt ones row (1024)
__global__ void k_misc(const float* __restrict__ x, unsigned short* __restrict__ xb,
                       const float* __restrict__ proj, unsigned short* __restrict__ projB,
                       unsigned short* __restrict__ Vt){
  int bx = blockIdx.x, tid = threadIdx.x;
  if(bx < 16384){
    int i = bx*256 + tid;
    float4 v = ((const float4*)x)[i];
    us4 o = {f2bf(v.x),f2bf(v.y),f2bf(v.z),f2bf(v.w)};
    ((us4*)xb)[i]=o;
  } else if(bx < 16400){
    int i = (bx-16384)*256 + tid;
    if(i<4096){ float4 v = ((const float4*)proj)[i];
      us4 o = {f2bf(v.x),f2bf(v.y),f2bf(v.z),f2bf(v.w)};
      ((us4*)projB)[i]=o; }
  } else {
    int i = (bx-16400)*256 + tid;      // 64*4096
    int head=i>>12, n=i&4095;
    Vt[((size_t)head*80+64)*4096 + n] = 0x3F80;
  }
}

// ---------------- QKV projection ----------------
__global__ __launch_bounds__(256,2) void k_qkv(const unsigned short* __restrict__ xb,
    const unsigned short* __restrict__ wqkvT,
    const float* __restrict__ bq, const float* __restrict__ bk, const float* __restrict__ bv,
    unsigned short* __restrict__ Qb, unsigned short* __restrict__ Kb, unsigned short* __restrict__ Vt){
  __shared__ __align__(16) unsigned short As[128*64];
  __shared__ __align__(16) unsigned short Bs[128*64];
  facc4 acc[4][4]; ZERO_ACC(acc,4,4)
  const int bm = blockIdx.x, bn = blockIdx.y;
  gemm_core<128,128,2,2>(xb + (size_t)bm*128*1024, 1024,
                         wqkvT + (size_t)bn*128*1024, 1024, 16, As, Bs, acc);
  const int tid=threadIdx.x, w=tid>>6, lane=tid&63, col=lane&15, quad=lane>>4;
  const int wr=w>>1, wc=w&1;
  #pragma unroll
  for(int i=0;i<4;++i){
    int row0 = bm*128 + wr*64 + i*16 + quad*4;
    int bb = row0 >> 12, n0 = row0 & 4095;
    #pragma unroll
    for(int j=0;j<4;++j){
      int c = bn*128 + wc*64 + j*16 + col;
      int region = c >> 10, f = c & 1023, he = f >> 6, hd = f & 63;
      const float* bias = (region==0)? bq : (region==1)? bk : bv;
      float bsv = bias[f];
      if(region < 2){
        unsigned short* dst = (region==0? Qb : Kb) + ((size_t)(bb*16+he)*4096 + n0)*64 + hd;
        #pragma unroll
        for(int r=0;r<4;++r) dst[(size_t)r*64] = f2bf(acc[i][j][r] + bsv);
      } else {
        us4 pk;
        #pragma unroll
        for(int r=0;r<4;++r) pk[r] = f2bf(acc[i][j][r] + bsv);
        *(us4*)(Vt + ((size_t)(bb*16+he)*80 + hd)*4096 + n0) = pk;
      }
    }
  }
}

// ---------------- FAVOR+ features: 128x256 tiles, repacked coalesced output ----
__global__ __launch_bounds__(256,2) void k_featq(const unsigned short* __restrict__ Qb,
    const unsigned short* __restrict__ projB, unsigned short* __restrict__ Qp, int qbase){
  __shared__ __align__(16) unsigned short As[128*64];
  __shared__ __align__(16) unsigned short Bs[256*64];
  __shared__ float diagS[128];
  __shared__ float maxS[128][2];
  facc4 acc[4][8]; ZERO_ACC(acc,4,8)
  const int br = blockIdx.x;                       // 512 blocks/quarter
  gemm_core<128,256,2,2>(Qb + ((size_t)qbase*65536 + (size_t)br*128)*64, 64,
                         projB, 64, 1, As, Bs, acc);
  const int tid=threadIdx.x, w=tid>>6, lane=tid&63, col=lane&15, quad=lane>>4;
  const int wr=w>>1, wc=w&1;
  if(tid<128){ float ss=0.f;
    #pragma unroll
    for(int kg=0;kg<8;++kg){ frag8 v = frag_ld(As, tid, kg);
      #pragma unroll
      for(int e=0;e<8;++e){ float f=bf2f((unsigned short)v[e]); ss+=f*f; } }
    diagS[tid]=0.0625f*ss; }
  #pragma unroll
  for(int i=0;i<4;++i)
    #pragma unroll
    for(int r=0;r<4;++r){
      float m=-1e30f;
      #pragma unroll
      for(int j=0;j<8;++j) m=fmaxf(m,acc[i][j][r]);
      #pragma unroll
      for(int d=1;d<16;d<<=1) m=fmaxf(m,__shfl_xor(m,d));
      if(col==0) maxS[wr*64+i*16+quad*4+r][wc]=m;
    }
  __syncthreads();
  const float dn=0.35355339059327378f;
  unsigned short* Ct = Bs;                         // 64 rows x 256 per pass = 32 KB
  size_t tokbase = (size_t)br*128;
  #pragma unroll
  for(int p=0;p<2;++p){
    if(wr==p){
      #pragma unroll
      for(int i=0;i<4;++i)
        #pragma unroll
        for(int r=0;r<4;++r){
          int tl = i*16+quad*4+r;                  // local row in pass
          int tf = p*64+tl;
          float dsub = diagS[tf] + dn*fmaxf(maxS[tf][0],maxS[tf][1]);
          #pragma unroll
          for(int j=0;j<8;++j){
            int m = wc*128 + j*16 + col;
            float val = 0.0625f*(__expf(dn*acc[i][j][r] - dsub) + 1e-4f);
            int cc = m>>3;
            Ct[tl*256 + ((cc ^ (tl&31))<<3) + (m&7)] = f2bf(val);
          }
        }
    }
    __syncthreads();
    for(int c=tid;c<2048;c+=256){
      int tl=c>>5, part=c&31;
      us8 v = *(const us8*)(Ct + tl*256 + ((part ^ (tl&31))<<3));
      *(us8*)(Qp + (tokbase + p*64 + tl)*256 + part*8) = v;
    }
    __syncthreads();
  }
}

__global__ __launch_bounds__(256,2) void k_fkmax(const unsigned short* __restrict__ Kb,
    const unsigned short* __restrict__ projB, float* __restrict__ pmax){
  __shared__ __align__(16) unsigned short As[128*64];
  __shared__ __align__(16) unsigned short Bs[256*64];
  __shared__ float wm[4];
  facc4 acc[4][8]; ZERO_ACC(acc,4,8)
  const int br = blockIdx.x;                       // 2048 blocks (all heads)
  gemm_core<128,256,2,2>(Kb + (size_t)br*8192, 64, projB, 64, 1, As, Bs, acc);
  const int w=threadIdx.x>>6, lane=threadIdx.x&63;
  float m=-1e30f;
  #pragma unroll
  for(int i=0;i<4;++i)
    #pragma unroll
    for(int j=0;j<8;++j)
      #pragma unroll
      for(int r=0;r<4;++r) m=fmaxf(m, acc[i][j][r]);
  #pragma unroll
  for(int d=1; d<64; d<<=1) m=fmaxf(m, __shfl_xor(m,d));
  if(lane==0) wm[w]=m;
  __syncthreads();
  if(threadIdx.x==0)
    pmax[br] = fmaxf(fmaxf(wm[0],wm[1]),fmaxf(wm[2],wm[3])) * 0.35355339059327378f;
}

__global__ void k_mxk(const float* __restrict__ pmax, float* __restrict__ mxK){
  int h = threadIdx.x;  // 64
  float m=-1e30f;
  for(int i=0;i<32;++i) m=fmaxf(m, pmax[h*32+i]);
  mxK[h]=m;
}

__global__ __launch_bounds__(256,2) void k_featk(const unsigned short* __restrict__ Kb,
    const unsigned short* __restrict__ projB, const float* __restrict__ mxK,
    unsigned short* __restrict__ KpT, int qbase){
  __shared__ __align__(16) unsigned short As[128*64];
  __shared__ __align__(16) unsigned short Bs[256*64];
  __shared__ float diagS[128];
  facc4 acc[4][8]; ZERO_ACC(acc,4,8)
  const int br = blockIdx.x;                       // 512 blocks/quarter
  gemm_core<128,256,2,2>(Kb + ((size_t)qbase*65536 + (size_t)br*128)*64, 64,
                         projB, 64, 1, As, Bs, acc);
  const int tid=threadIdx.x, w=tid>>6, lane=tid&63, col=lane&15, quad=lane>>4;
  const int wr=w>>1, wc=w&1;
  if(tid<128){ float ss=0.f;
    #pragma unroll
    for(int kg=0;kg<8;++kg){ frag8 v = frag_ld(As, tid, kg);
      #pragma unroll
      for(int e=0;e<8;++e){ float f=bf2f((unsigned short)v[e]); ss+=f*f; } }
    diagS[tid]=0.0625f*ss; }
  __syncthreads();
  const int lh = br>>5, n0 = (br&31)*128;
  const float mxh = mxK[qbase*16 + lh];
  const float dn=0.35355339059327378f;
  unsigned short* Ct = Bs;                         // 128 m-rows x 128 tok = 32 KB/pass
  #pragma unroll
  for(int p=0;p<2;++p){
    if(wc==p){
      #pragma unroll
      for(int i=0;i<4;++i)
        #pragma unroll
        for(int r=0;r<4;++r){
          int tok = wr*64 + i*16 + quad*4 + r;     // 0..127
          float dsub = diagS[tok] + mxh;
          int tc = tok>>3;
          #pragma unroll
          for(int j=0;j<8;++j){
            int ml = j*16 + col;                   // 0..127 local m
            float val = 0.0625f*(__expf(dn*acc[i][j][r] - dsub) + 1e-4f);
            Ct[ml*128 + ((tc ^ (ml&15))<<3) + (tok&7)] = f2bf(val);
          }
        }
    }
    __syncthreads();
    for(int c=tid;c<2048;c+=256){
      int ml=c>>4, part=c&15;
      us8 v = *(const us8*)(Ct + ml*128 + ((part ^ (ml&15))<<3));
      *(us8*)(KpT + ((size_t)(lh*256 + p*128 + ml))*4096 + n0 + part*8) = v;
    }
    __syncthreads();
  }
}

// ---------------- kv = Kp^T V (split-K 16 over tokens), +ones row ----------------
__global__ __launch_bounds__(256,2) void k_kv(const unsigned short* __restrict__ KpT,
    const unsigned short* __restrict__ Vt, float* __restrict__ part, int qbase){
  __shared__ __align__(16) unsigned short As[256*64];
  __shared__ __align__(16) unsigned short Bs[80*64];
  facc4 acc[4][5]; ZERO_ACC(acc,4,5)
  const int ksp = blockIdx.x, lh = blockIdx.y;     // 16 x 16
  gemm_core<256,80,4,1>(KpT + (size_t)lh*1048576 + ksp*256, 4096,
                        Vt  + ((size_t)(qbase*16+lh))*327680 + ksp*256, 4096, 4, As, Bs, acc);
  const int w=threadIdx.x>>6, lane=threadIdx.x&63, col=lane&15, quad=lane>>4;
  #pragma unroll
  for(int i=0;i<4;++i){
    int mp0 = w*64 + i*16 + quad*4;
    #pragma unroll
    for(int j=0;j<5;++j){
      int d = j*16+col;
      *(facc4*)(part + (((size_t)(ksp*16 + lh))*80 + d)*256 + mp0) = acc[i][j];
    }
  }
}

__global__ void k_kvred(const float* __restrict__ part, unsigned short* __restrict__ kvT, int qbase){
  int i = blockIdx.x*256 + threadIdx.x;            // 81920 float4 groups
  float4 s = {0.f,0.f,0.f,0.f};
  #pragma unroll
  for(int ks=0;ks<16;++ks){ float4 v = ((const float4*)part)[(size_t)ks*81920 + i];
    s.x+=v.x; s.y+=v.y; s.z+=v.z; s.w+=v.w; }
  us4 o = {f2bf(s.x),f2bf(s.y),f2bf(s.z),f2bf(s.w)};
  ((us4*)kvT)[(size_t)qbase*81920 + i] = o;
}

// ---------------- attn = Qp kv / (Qp s), repacked coalesced output -------------
__global__ __launch_bounds__(256,2) void k_attn(const unsigned short* __restrict__ Qp,
    const unsigned short* __restrict__ kvT, unsigned short* __restrict__ attnOut, int qbase){
  __shared__ __align__(16) unsigned short As[128*64];
  __shared__ __align__(16) unsigned short Bs[80*64];
  facc4 acc[2][5]; ZERO_ACC(acc,2,5)
  const int mb = blockIdx.x, lh = blockIdx.y;      // 32 x 16
  gemm_core<128,80,4,1>(Qp  + (size_t)lh*1048576 + (size_t)mb*32768, 256,
                        kvT + ((size_t)(qbase*16+lh))*20480, 256, 4, As, Bs, acc);
  const int w=threadIdx.x>>6, lane=threadIdx.x&63, col=lane&15, quad=lane>>4;
  const int gh = qbase*16 + lh, b = gh>>4, h = gh&15;
  unsigned short* Ct = As;                         // 128 x 64 = 16 KB
  #pragma unroll
  for(int i=0;i<2;++i)
    #pragma unroll
    for(int r=0;r<4;++r){
      float den = __shfl(acc[i][4][r], lane & 48);
      float inv = 1.0f/den;
      int tok = w*32 + i*16 + quad*4 + r;
      #pragma unroll
      for(int j=0;j<4;++j){
        int hd = j*16 + col;
        int cc = hd>>3;
        Ct[tok*64 + ((cc ^ (tok&7))<<3) + (hd&7)] = f2bf(acc[i][j][r]*inv);
      }
    }
  __syncthreads();
  const int n0 = mb*128;
  for(int c=threadIdx.x;c<1024;c+=256){
    int row=c>>3, part=c&7;
    us8 v = *(const us8*)(Ct + row*64 + ((part ^ (row&7))<<3));
    *(us8*)(attnOut + ((size_t)(b*4096) + n0 + row)*1024 + h*64 + part*8) = v;
  }
}

// ---------------- output projection + residual (y1 bf16) ----------------
__global__ __launch_bounds__(256,2) void k_oproj(const unsigned short* __restrict__ attnOut,
    const unsigned short* __restrict__ woT, const float* __restrict__ bo,
    const float* __restrict__ x, unsigned short* __restrict__ y1){
  __shared__ __align__(16) unsigned short As[128*64];
  __shared__ __align__(16) unsigned short Bs[128*64];
  facc4 acc[4][4]; ZERO_ACC(acc,4,4)
  const int bm = blockIdx.x, bn = blockIdx.y;
  gemm_core<128,128,2,2>(attnOut + (size_t)bm*128*1024, 1024,
                         woT + (size_t)bn*128*1024, 1024, 16, As, Bs, acc);
  const int tid=threadIdx.x, w=tid>>6, lane=tid&63, col=lane&15, quad=lane>>4;
  const int wr=w>>1, wc=w&1;
  #pragma unroll
  for(int i=0;i<4;++i){
    int row0 = bm*128 + wr*64 + i*16 + quad*4;
    #pragma unroll
    for(int j=0;j<4;++j){
      int c = bn*128 + wc*64 + j*16 + col;
      float bsv = bo[c];
      #pragma unroll
      for(int r=0;r<4;++r){
        size_t idx = (size_t)(row0+r)*1024 + c;
        y1[idx] = f2bf(acc[i][j][r] + bsv + x[idx]);
      }
    }
  }
}

// ---------------- FFN (halved) ----------------
__global__ __launch_bounds__(256,2) void k_ffn1(const unsigned short* __restrict__ xb2,
    const unsigned short* __restrict__ w1T, const float* __restrict__ b1,
    unsigned short* __restrict__ hbuf, int hbase){
  __shared__ __align__(16) unsigned short As[128*64];
  __shared__ __align__(16) unsigned short Bs[128*64];
  facc4 acc[4][4]; ZERO_ACC(acc,4,4)
  const int bm = blockIdx.x, bn = blockIdx.y;      // 64 x 32
  gemm_core<128,128,2,2>(xb2 + ((size_t)(hbase*64 + bm))*131072, 1024,
                         w1T + (size_t)bn*128*1024, 1024, 16, As, Bs, acc);
  const int tid=threadIdx.x, w=tid>>6, lane=tid&63, col=lane&15, quad=lane>>4;
  const int wr=w>>1, wc=w&1;
  #pragma unroll
  for(int i=0;i<4;++i){
    int lrow0 = bm*128 + wr*64 + i*16 + quad*4;
    #pragma unroll
    for(int j=0;j<4;++j){
      int c = bn*128 + wc*64 + j*16 + col;
      float bsv = b1[c];
      #pragma unroll
      for(int r=0;r<4;++r){
        float v = acc[i][j][r] + bsv;
        float g = 0.5f*v*(1.0f+erff(v*0.70710678118654752f));   // exact GELU
        hbuf[(size_t)(lrow0+r)*4096 + c] = f2bf(g);
      }
    }
  }
}

__global__ __launch_bounds__(256,2) void k_ffn2(const unsigned short* __restrict__ hbuf,
    const unsigned short* __restrict__ w2T, const float* __restrict__ b2,
    const unsigned short* __restrict__ xb2, unsigned short* __restrict__ y2, int hbase){
  __shared__ __align__(16) unsigned short As[128*64];
  __shared__ __align__(16) unsigned short Bs[128*64];
  facc4 acc[4][4]; ZERO_ACC(acc,4,4)
  const int bm = blockIdx.x, bn = blockIdx.y;      // 64 x 8
  gemm_core<128,128,2,2>(hbuf + (size_t)bm*128*4096, 4096,
                         w2T + (size_t)bn*128*4096, 4096, 64, As, Bs, acc);
  const int tid=threadIdx.x, w=tid>>6, lane=tid&63, col=lane&15, quad=lane>>4;
  const int wr=w>>1, wc=w&1;
  #pragma unroll
  for(int i=0;i<4;++i){
    int grow0 = hbase*8192 + bm*128 + wr*64 + i*16 + quad*4;
    #pragma unroll
    for(int j=0;j<4;++j){
      int c = bn*128 + wc*64 + j*16 + col;
      float bsv = b2[c];
      #pragma unroll
      for(int r=0;r<4;++r){
        size_t idx = (size_t)(grow0+r)*1024 + c;
        y2[idx] = f2bf(acc[i][j][r] + bsv + bf2f(xb2[idx]));
      }
    }
  }
}

// ---------------- LayerNorm: bf16 in, wave-per-row -------------------------
__global__ __launch_bounds__(256) void k_lnb(const unsigned short* __restrict__ in,
    const float* __restrict__ g, const float* __restrict__ b,
    float* __restrict__ outf, unsigned short* __restrict__ outb){
  const int row = blockIdx.x*4 + (threadIdx.x>>6);
  const int lane = threadIdx.x&63;
  const unsigned short* x = in + (size_t)row*1024 + lane*16;
  float v[16];
  float s=0.f, s2=0.f;
  #pragma unroll
  for(int q=0;q<2;++q){ us8 u = *(const us8*)(x + q*8);
    #pragma unroll
    for(int e=0;e<8;++e){ float f=bf2f(u[e]); v[q*8+e]=f; s+=f; s2+=f*f; } }
  #pragma unroll
  for(int d=32;d;d>>=1){ s+=__shfl_xor(s,d); s2+=__shfl_xor(s2,d); }
  float mu = s*(1.0f/1024.0f), var = s2*(1.0f/1024.0f)-mu*mu;
  float rinv = rsqrtf(var+1e-5f);
  const int cb = lane*16;
  if(outf){
    #pragma unroll
    for(int q=0;q<4;++q){
      float4 o;
      o.x=(v[q*4+0]-mu)*rinv*g[cb+q*4+0]+b[cb+q*4+0];
      o.y=(v[q*4+1]-mu)*rinv*g[cb+q*4+1]+b[cb+q*4+1];
      o.z=(v[q*4+2]-mu)*rinv*g[cb+q*4+2]+b[cb+q*4+2];
      o.w=(v[q*4+3]-mu)*rinv*g[cb+q*4+3]+b[cb+q*4+3];
      *(float4*)(outf + (size_t)row*1024 + cb + q*4) = o;
    }
  }
  if(outb){
    #pragma unroll
    for(int q=0;q<2;++q){
      us8 o;
      #pragma unroll
      for(int e=0;e<8;++e) o[e]=f2bf((v[q*8+e]-mu)*rinv*g[cb+q*8+e]+b[cb+q*8+e]);
      *(us8*)(outb + (size_t)row*1024 + cb + q*8) = o;
    }
  }
}

// ---------------- launch ----------------
extern "C" void kernel_launch(void* const* d_in, const int* in_sizes, int n_in,
                              void* d_out, int out_size, void* d_ws, size_t ws_size,
                              hipStream_t stream){
  const float* x   = (const float*)d_in[0];
  const float* wq  = (const float*)d_in[1];
  const float* bq  = (const float*)d_in[2];
  const float* wk  = (const float*)d_in[3];
  const float* bk  = (const float*)d_in[4];
  const float* wv  = (const float*)d_in[5];
  const float* bv  = (const float*)d_in[6];
  const float* wo  = (const float*)d_in[7];
  const float* bo  = (const float*)d_in[8];
  const float* proj= (const float*)d_in[9];
  const float* w1  = (const float*)d_in[10];
  const float* b1  = (const float*)d_in[11];
  const float* w2  = (const float*)d_in[12];
  const float* b2  = (const float*)d_in[13];
  const float* ln1g= (const float*)d_in[14];
  const float* ln1b= (const float*)d_in[15];
  const float* ln2g= (const float*)d_in[16];
  const float* ln2b= (const float*)d_in[17];
  (void)in_sizes; (void)n_in; (void)out_size;

  char* ws = (char*)d_ws;
  size_t off = 0;
  auto alloc = [&](size_t bytes)->char*{ char* p = ws + off; off += (bytes + 255) & ~(size_t)255; return p; };
  unsigned short* wqkvT = (unsigned short*)alloc(6291456);
  unsigned short* woT   = (unsigned short*)alloc(2097152);
  unsigned short* w1T   = (unsigned short*)alloc(8388608);
  unsigned short* w2T   = (unsigned short*)alloc(8388608);
  unsigned short* projB = (unsigned short*)alloc(32768);
  unsigned short* kvT   = (unsigned short*)alloc(2621440);
  float* pmax = (float*)alloc(16384);
  float* mxK  = (float*)alloc(256);
  char* R = alloc(230686720ull);
  if (off > ws_size) return;

  unsigned short* xb   = (unsigned short*)R;
  unsigned short* Qp   = (unsigned short*)R;
  unsigned short* Qb   = (unsigned short*)(R + 33554432);
  unsigned short* xb2  = (unsigned short*)(R + 33554432);
  unsigned short* Kb   = (unsigned short*)(R + 67108864);
  unsigned short* hbuf = (unsigned short*)(R + 67108864);
  unsigned short* Vt   = (unsigned short*)(R + 100663296);
  unsigned short* KpT  = (unsigned short*)(R + 142606336);
  float*          kvpart = (float*)(R + 176160768);
  unsigned short* attnOut = (unsigned short*)(R + 197132288);
  unsigned short* y2   = (unsigned short*)(R + 197132288);
  unsigned short* y1   = (unsigned short*)R;

  dim3 blk(256);
  k_transpose4<<<dim3(16,16,4),blk,0,stream>>>(wq, wk, wv, wo, wqkvT, woT);
  k_transpose<<<dim3(64,16),blk,0,stream>>>(w1, w1T, 1024, 4096);
  k_transpose<<<dim3(16,64),blk,0,stream>>>(w2, w2T, 4096, 1024);
  k_misc<<<17424,blk,0,stream>>>(x, xb, proj, projB, Vt);

  k_qkv<<<dim3(128,24),blk,0,stream>>>(xb, wqkvT, bq, bk, bv, Qb, Kb, Vt);
  k_fkmax<<<2048,blk,0,stream>>>(Kb, projB, pmax);
  k_mxk<<<1,64,0,stream>>>(pmax, mxK);

  for (int q = 0; q < 4; ++q) {
    k_featq<<<512,blk,0,stream>>>(Qb, projB, Qp, q);
    k_featk<<<512,blk,0,stream>>>(Kb, projB, mxK, KpT, q);
    k_kv<<<dim3(16,16),blk,0,stream>>>(KpT, Vt, kvpart, q);
    k_kvred<<<320,blk,0,stream>>>(kvpart, kvT, q);
    k_attn<<<dim3(32,16),blk,0,stream>>>(Qp, kvT, attnOut, q);
  }

  k_oproj<<<dim3(128,8),blk,0,stream>>>(attnOut, woT, bo, x, y1);
  k_lnb<<<4096,blk,0,stream>>>(y1, ln1g, ln1b, nullptr, xb2);

  for (int h = 0; h < 2; ++h) {
    k_ffn1<<<dim3(64,32),blk,0,stream>>>(xb2, w1T, b1, hbuf, h);
    k_ffn2<<<dim3(64,8),blk,0,stream>>>(hbuf, w2T, b2, xb2, y2, h);
  }
  k_lnb<<<4096,blk,0,stream>>>(y2, ln2g, ln2b, (float*)d_out, nullptr);
}